// Round 7
// baseline (409.815 us; speedup 1.0000x reference)
//
#include <hip/hip_runtime.h>

#define NB 1024
#define NNODE 200
#define NN2 40000
#define HD 128
#define KTOP 8000
#define NCH 7     // i-chunks of 32 (224 padded)
#define NJT 13    // j-tiles of 16 (208 padded)
#define XBS 232   // xb row stride (elems; 464 B; dword stride 116 == 20 mod 32 -> 2-way free)
#define A2S 40    // a2t row stride (80 B; dword stride 20 -> 2-way free)

#define WLO_BITS 0x3F47AE14u  // 0.78f
#define WHI_BITS 0x3F51EB85u  // 0.82f
#define CCAP 3072
#define C2CAP 64

typedef __attribute__((ext_vector_type(8))) short short8;
typedef __attribute__((ext_vector_type(4))) float f32x4;

__device__ __forceinline__ unsigned short f2bf(float f) {
  unsigned u = __float_as_uint(f);
  u = u + 0x7FFFu + ((u >> 16) & 1u);
  return (unsigned short)(u >> 16);
}

// JAX top_k selection predicate: value bits desc, flat index asc
__device__ __forceinline__ float maskv(float v, int idx, unsigned vt, int it) {
  unsigned b = __float_as_uint(v);
  return (b > vt || (b == vt && idx <= it)) ? v : 0.0f;
}

// ===== K0: pack W1 (200x128 f32) into bf16 B-fragment order ================
// frag t = (ks*8 + ht)*64 + lane; elem j: B[k=ks*32+(lane>>4)*8+j][h=ht*16+(lane&15)]
__global__ void k_weights(const float* __restrict__ W1, unsigned short* __restrict__ wf) {
  int t = blockIdx.x * 256 + threadIdx.x;
  if (t >= NCH * 8 * 64) return;
  int lane = t & 63;
  int ht = (t >> 6) & 7;
  int ks = t >> 9;
  int c = lane & 15, q = lane >> 4;
  int h = ht * 16 + c;
  unsigned short v[8];
#pragma unroll
  for (int j = 0; j < 8; ++j) {
    int k = ks * 32 + q * 8 + j;
    v[j] = f2bf((k < NNODE) ? W1[k * HD + h] : 0.0f);
  }
  uint4 u;
  u.x = (unsigned)v[0] | ((unsigned)v[1] << 16);
  u.y = (unsigned)v[2] | ((unsigned)v[3] << 16);
  u.z = (unsigned)v[4] | ((unsigned)v[5] << 16);
  u.w = (unsigned)v[6] | ((unsigned)v[7] << 16);
  ((uint4*)wf)[t] = u;
}

// ===== K1: per-sample exact top-8000 threshold + dinv, single x pass =======
// Standalone (34 KB LDS -> 4 blocks/CU). R5 lesson: fusing this with the GEMM
// kernel forced it to 2 blocks/CU (66 KB union) and cost ~60 us.
__global__ __launch_bounds__(512) void k_prep(const float* __restrict__ x,
                                              unsigned* __restrict__ vtit,
                                              float* __restrict__ dinv_g) {
  __shared__ union {
    struct { unsigned cb[CCAP]; int ci[CCAP]; } w;  // 24 KB (window + fallback cands)
    unsigned hist[4096];                            // 16 KB (fallback pass 1)
  } u;
  __shared__ unsigned sub[1024];
  __shared__ unsigned csum[512];
  __shared__ float degf[NNODE];
  __shared__ unsigned c2b[C2CAP];
  __shared__ int c2i[C2CAP];
  __shared__ int sc[4];
  __shared__ int cnt, cnt2, nhi_s, fbflag;
  __shared__ unsigned svt;
  __shared__ int sit;

  const int s = blockIdx.x, tid = threadIdx.x;
  const float* xp = x + (size_t)s * NN2;
  const float4* xp4 = (const float4*)xp;

  if (tid < NNODE) degf[tid] = 0.0f;
  if (tid == 0) { cnt = 0; cnt2 = 0; nhi_s = 0; fbflag = 0; }
  __syncthreads();

  // ---- single streaming pass: sure-colsums + window candidates + n_hi ----
  // unroll 4: batch independent float4 loads for MLP (prep is latency-bound,
  // 1.8 TB/s at R6)
  int nhi = 0;
#pragma unroll 4
  for (int e = tid; e < NN2 / 4; e += 512) {
    float4 f = xp4[e];
    int base = e * 4;
    float vv[4] = {f.x, f.y, f.z, f.w};
#pragma unroll
    for (int k = 0; k < 4; ++k) {
      unsigned bits = __float_as_uint(vv[k]);
      if (bits > WHI_BITS) {
        atomicAdd(&degf[(base + k) % NNODE], vv[k]);
        ++nhi;
      } else if (bits >= WLO_BITS) {
        int p = atomicAdd(&cnt, 1);
        if (p < CCAP) { u.w.cb[p] = bits; u.w.ci[p] = base + k; }
      }
    }
  }
#pragma unroll
  for (int m = 1; m < 64; m <<= 1) nhi += __shfl_xor(nhi, m);
  if ((tid & 63) == 0) atomicAdd(&nhi_s, nhi);
  __syncthreads();

  const int need = KTOP - nhi_s;
  const int c = cnt;
  bool window_ok = (need >= 1) && (c <= CCAP) && (need <= c);

  if (window_ok) {
    // ---- exact rank within candidates via sub-histogram on bits[21:12] ----
    for (int e = tid; e < 1024; e += 512) sub[e] = 0u;
    __syncthreads();
    for (int t = tid; t < c; t += 512) atomicAdd(&sub[(u.w.cb[t] >> 12) & 1023u], 1u);
    __syncthreads();
    if (tid < 128) {
      unsigned ss = 0;
#pragma unroll
      for (int k = 0; k < 8; ++k) ss += sub[tid * 8 + k];
      csum[tid] = ss;
    }
    __syncthreads();
    if (tid == 0) {
      int cum = 0, b2 = 0, need2 = need;
      for (int t = 127; t >= 0; --t) {
        int cs = (int)csum[t];
        if (cum + cs >= need) {
          for (int b = t * 8 + 7; b >= t * 8; --b) {
            int hb = (int)sub[b];
            if (cum + hb >= need) { b2 = b; need2 = need - cum; break; }
            cum += hb;
          }
          break;
        }
        cum += cs;
      }
      sc[0] = b2;
      sc[1] = need2;
    }
    __syncthreads();
    const unsigned b2 = (unsigned)sc[0];
    const int need2 = sc[1];
    for (int t = tid; t < c; t += 512) {
      if (((u.w.cb[t] >> 12) & 1023u) == b2) {
        int p = atomicAdd(&cnt2, 1);
        if (p < C2CAP) { c2b[p] = u.w.cb[t]; c2i[p] = u.w.ci[t]; }
      }
    }
    __syncthreads();
    if (cnt2 > C2CAP) {
      if (tid == 0) fbflag = 1;
    } else {
      const int c2 = cnt2;
      for (int t = tid; t < c2; t += 512) {
        unsigned vb = c2b[t];
        int vi = c2i[t];
        int rank = 0;
        for (int uu = 0; uu < c2; ++uu) {
          unsigned ub = c2b[uu];
          if (ub > vb || (ub == vb && c2i[uu] < vi)) ++rank;
        }
        if (rank == need2 - 1) { svt = vb; sit = vi; }
      }
    }
    __syncthreads();
    if (!fbflag) {
      const unsigned vt = svt;
      const int itx = sit;
      for (int t = tid; t < c; t += 512) {
        unsigned bits = u.w.cb[t];
        int e = u.w.ci[t];
        if (bits > vt || (bits == vt && e <= itx))
          atomicAdd(&degf[e % NNODE], __uint_as_float(bits));
      }
    }
  } else {
    if (tid == 0) fbflag = 1;
    __syncthreads();  // match barrier count shape (block-uniform anyway)
  }
  __syncthreads();

  if (fbflag) {
    // ================= fallback: verified two-pass radix select ============
    if (tid < NNODE) degf[tid] = 0.0f;
    for (int e = tid; e < 4096; e += 512) u.hist[e] = 0u;
    if (tid == 0) { cnt = 0; cnt2 = 0; }
    __syncthreads();
    for (int e = tid; e < NN2 / 4; e += 512) {
      float4 f = xp4[e];
      atomicAdd(&u.hist[__float_as_uint(f.x) >> 18], 1u);
      atomicAdd(&u.hist[__float_as_uint(f.y) >> 18], 1u);
      atomicAdd(&u.hist[__float_as_uint(f.z) >> 18], 1u);
      atomicAdd(&u.hist[__float_as_uint(f.w) >> 18], 1u);
    }
    __syncthreads();
    {
      unsigned ss = 0;
#pragma unroll
      for (int k = 0; k < 8; ++k) ss += u.hist[tid * 8 + k];
      csum[tid] = ss;
    }
    __syncthreads();
    if (tid == 0) {
      int cum = 0, bsel = 0, nd = KTOP;
      for (int t = 511; t >= 0; --t) {
        int cs = (int)csum[t];
        if (cum + cs >= KTOP) {
          for (int b = t * 8 + 7; b >= t * 8; --b) {
            int hb = (int)u.hist[b];
            if (cum + hb >= KTOP) { bsel = b; nd = KTOP - cum; break; }
            cum += hb;
          }
          break;
        }
        cum += cs;
      }
      sc[0] = bsel;
      sc[1] = nd;
    }
    __syncthreads();
    const int bsel = sc[0], nd = sc[1];
    // pass 2: candidates (bucket==bsel) + sure colsums (bucket>bsel)
    for (int e = tid; e < NN2 / 4; e += 512) {
      float4 f = xp4[e];
      int base = e * 4;
      float vv[4] = {f.x, f.y, f.z, f.w};
#pragma unroll
      for (int k = 0; k < 4; ++k) {
        unsigned bits = __float_as_uint(vv[k]);
        int bk = (int)(bits >> 18);
        if (bk > bsel) {
          atomicAdd(&degf[(base + k) % NNODE], vv[k]);
        } else if (bk == bsel) {
          int p = atomicAdd(&cnt, 1);
          if (p < CCAP) { u.w.cb[p] = bits; u.w.ci[p] = base + k; }
        }
      }
    }
    for (int e = tid; e < 1024; e += 512) sub[e] = 0u;
    __syncthreads();
    const int cc = cnt < CCAP ? cnt : CCAP;
    for (int t = tid; t < cc; t += 512) atomicAdd(&sub[(u.w.cb[t] >> 8) & 1023u], 1u);
    __syncthreads();
    if (tid < 128) {
      unsigned ss = 0;
#pragma unroll
      for (int k = 0; k < 8; ++k) ss += sub[tid * 8 + k];
      csum[tid] = ss;
    }
    __syncthreads();
    if (tid == 0) {
      int cum = 0, b2 = 0, need2 = nd;
      for (int t = 127; t >= 0; --t) {
        int cs = (int)csum[t];
        if (cum + cs >= nd) {
          for (int b = t * 8 + 7; b >= t * 8; --b) {
            int hb = (int)sub[b];
            if (cum + hb >= nd) { b2 = b; need2 = nd - cum; break; }
            cum += hb;
          }
          break;
        }
        cum += cs;
      }
      sc[2] = b2;
      sc[3] = need2;
    }
    __syncthreads();
    const unsigned key = ((unsigned)bsel << 10) | (unsigned)sc[2];
    const int need2 = sc[3];
    for (int t = tid; t < cc; t += 512) {
      if ((u.w.cb[t] >> 8) == key) {
        int p = atomicAdd(&cnt2, 1);
        if (p < C2CAP) { c2b[p] = u.w.cb[t]; c2i[p] = u.w.ci[t]; }
      }
    }
    __syncthreads();
    {
      int c2 = cnt2 < C2CAP ? cnt2 : C2CAP;
      for (int t = tid; t < c2; t += 512) {
        unsigned vb = c2b[t];
        int vi = c2i[t];
        int rank = 0;
        for (int uu = 0; uu < c2; ++uu) {
          unsigned ub = c2b[uu];
          if (ub > vb || (ub == vb && c2i[uu] < vi)) ++rank;
        }
        if (rank == need2 - 1) { svt = vb; sit = vi; }
      }
    }
    __syncthreads();
    const unsigned vt = svt;
    const int itx = sit;
    for (int t = tid; t < cc; t += 512) {
      unsigned bits = u.w.cb[t];
      int e = u.w.ci[t];
      if (bits > vt || (bits == vt && e <= itx))
        atomicAdd(&degf[e % NNODE], __uint_as_float(bits));
    }
    __syncthreads();
  }

  if (tid < NNODE) dinv_g[s * NNODE + tid] = 1.0f / sqrtf(1.0f + degf[tid]);
  if (tid == 0) {
    vtit[s * 2 + 0] = svt;
    vtit[s * 2 + 1] = (unsigned)sit;
  }
}

// ---- staging macros (hand-inlined) -----------------------------------------
// T14 split: LOADs issue global reads into va/vb regs early; WRITEs convert
// and store to LDS later (latency hidden under MFMA).
#define STAGE_LOAD_A(ic_)                                              \
  {                                                                    \
    const int gi = (ic_)*32 + r_;                                      \
    const bool rowok = gi < NNODE;                                     \
    const int rb = gi * NNODE;                                         \
    _Pragma("unroll") for (int itc = 0; itc < 7; ++itc) {              \
      int col = c0_ + itc * 16; /* <=111, always valid */              \
      va[itc] = rowok ? xp[rb + col] : 0.0f;                           \
    }                                                                  \
  }

#define STAGE_LOAD_B(ic_)                                              \
  {                                                                    \
    const int gi = (ic_)*32 + r_;                                      \
    const bool rowok = gi < NNODE;                                     \
    const int rb = gi * NNODE;                                         \
    _Pragma("unroll") for (int itc = 7; itc < 13; ++itc) {             \
      int col = c0_ + itc * 16;                                        \
      vb[itc - 7] = (rowok && col < NNODE) ? xp[rb + col] : 0.0f;      \
    }                                                                  \
  }

#define STAGE_WRITE_A(ic_, bb_)                                        \
  {                                                                    \
    const int gi = (ic_)*32 + r_;                                      \
    const float di = dinv_l[gi];                                       \
    const int rb = gi * NNODE;                                         \
    rsA = 0.0f;                                                        \
    _Pragma("unroll") for (int itc = 0; itc < 7; ++itc) {              \
      int col = c0_ + itc * 16;                                        \
      float val = va[itc];                                             \
      unsigned short xbv = f2bf(val);                                  \
      float am = maskv(val, rb + col, vt, itx);                        \
      rsA += am * dinv_l[col];                                         \
      if (gi == col) am += 1.0f;                                       \
      xb[bb_][r_][col] = xbv;                                          \
      a2t[bb_][col][r_] = f2bf(am * di);                               \
    }                                                                  \
  }

#define STAGE_WRITE_B(ic_, bb_)                                        \
  {                                                                    \
    const int gi = (ic_)*32 + r_;                                      \
    const float di = dinv_l[gi];                                       \
    const int rb = gi * NNODE;                                         \
    float rs = rsA;                                                    \
    _Pragma("unroll") for (int itc = 7; itc < 13; ++itc) {             \
      int col = c0_ + itc * 16;                                        \
      unsigned short xbv = 0, a2v = 0;                                 \
      if (col < NNODE) {                                               \
        float val = vb[itc - 7];                                       \
        xbv = f2bf(val);                                               \
        float am = maskv(val, rb + col, vt, itx);                      \
        rs += am * dinv_l[col];                                        \
        if (gi == col) am += 1.0f;                                     \
        a2v = f2bf(am * di);                                           \
      }                                                                \
      xb[bb_][r_][col] = xbv;                                          \
      a2t[bb_][col][r_] = a2v;                                         \
    }                                                                  \
    xb[bb_][r_][208 + c0_] = 0; /* k-pad 208..223 */                   \
    rs += __shfl_xor(rs, 1);                                           \
    rs += __shfl_xor(rs, 2);                                           \
    rs += __shfl_xor(rs, 4);                                           \
    rs += __shfl_xor(rs, 8);                                           \
    if (c0_ == 0) atomicAdd(&rowsum[gi], rs);                          \
  }

// ===== K2: fused chain GEMM, wave-self-contained, shfl transpose ===========
// R6 lesson: bfr[7] persistent (28 VGPR) + T14 split overflowed the 128-reg
// budget -> 115 MB spill traffic. Fix: per-chunk wfr[] loads from precomputed
// wf (same address every chunk -> L1-hit), live only through GEMM1.
__global__ __launch_bounds__(512, 4) void k_main(
    const float* __restrict__ x, const unsigned short* __restrict__ wf,
    const float* __restrict__ b1, const float* __restrict__ W2,
    const float* __restrict__ b2, const unsigned* __restrict__ vtit,
    const float* __restrict__ dinv_g, float* __restrict__ out) {
  __shared__ unsigned short xb[2][32][XBS];    // x chunk bf16 [i][k]
  __shared__ unsigned short a2t[2][208][A2S];  // Ah_ij*dinv_i bf16 [j][i]
  __shared__ float rowsum[224];
  __shared__ float dinv_l[224];
  __shared__ float gs[HD];
  __shared__ float pt[4][HD];

  const int s = blockIdx.x;
  const int tid = threadIdx.x;
  const int lane = tid & 63;
  const int w = tid >> 6;  // wave 0..7 owns h-tile w
  const int c = lane & 15;
  const int q = lane >> 4;
  const float* xp = x + (size_t)s * NN2;
  const short8* wfp = (const short8*)wf;

  if (tid < 224) {
    dinv_l[tid] = (tid < NNODE) ? dinv_g[s * NNODE + tid] : 0.0f;
    rowsum[tid] = 0.0f;
  }
  const unsigned vt = vtit[s * 2];
  const int itx = (int)vtit[s * 2 + 1];
  const int r_ = tid >> 4, c0_ = tid & 15;

  float va[7], vb[6], rsA;

  // issue chunk-0 x loads immediately
  STAGE_LOAD_A(0);
  STAGE_LOAD_B(0);

  f32x4 acc2[NJT];
#pragma unroll
  for (int jt = 0; jt < NJT; ++jt) acc2[jt] = (f32x4){0.f, 0.f, 0.f, 0.f};

  __syncthreads();  // dinv_l ready
  STAGE_WRITE_A(0, 0);
  STAGE_WRITE_B(0, 0);
  __syncthreads();

  for (int ic = 0; ic < NCH; ++ic) {
    const int cur = ic & 1;
    const bool more = (ic + 1 < NCH);
    // W1 fragments for this chunk's GEMM1, issued FIRST (oldest in vm queue ->
    // MFMA's waitcnt doesn't drain the x loads behind them). L1-hit after ic=0.
    short8 wfr[NCH];
#pragma unroll
    for (int ks = 0; ks < NCH; ++ks) wfr[ks] = wfp[(ks * 8 + w) * 64 + lane];
    if (more) {
      STAGE_LOAD_A(ic + 1);  // issue early; consumed after GEMM1
      STAGE_LOAD_B(ic + 1);
    }
    // GEMM1: D(it)[i16][hc] for i-tiles 0,1 of this chunk, h-tile w
    f32x4 a0 = (f32x4){0.f, 0.f, 0.f, 0.f}, a1 = (f32x4){0.f, 0.f, 0.f, 0.f};
#pragma unroll
    for (int ks = 0; ks < NCH; ++ks) {
      short8 af0 = *(const short8*)&xb[cur][c][ks * 32 + q * 8];
      short8 af1 = *(const short8*)&xb[cur][16 + c][ks * 32 + q * 8];
      a0 = __builtin_amdgcn_mfma_f32_16x16x32_bf16(af0, wfr[ks], a0, 0, 0, 0);
      a1 = __builtin_amdgcn_mfma_f32_16x16x32_bf16(af1, wfr[ks], a1, 0, 0, 0);
    }
    if (more) STAGE_WRITE_A(ic + 1, cur ^ 1);  // va ready (GEMM1 covered latency)
    // pack C-layout rows (q*4+rg) to bf16 dword pairs
    unsigned pk0[2], pk1[2];
    pk0[0] = (unsigned)f2bf(a0[0]) | ((unsigned)f2bf(a0[1]) << 16);
    pk0[1] = (unsigned)f2bf(a0[2]) | ((unsigned)f2bf(a0[3]) << 16);
    pk1[0] = (unsigned)f2bf(a1[0]) | ((unsigned)f2bf(a1[1]) << 16);
    pk1[1] = (unsigned)f2bf(a1[2]) | ((unsigned)f2bf(a1[3]) << 16);
    // in-register transpose: C-layout -> GEMM2 B-fragment (k=i-local, n=h)
    union {
      unsigned u4[4];
      short8 s8;
    } ub;
#pragma unroll
    for (int d = 0; d < 4; ++d) {
      int src = c + (((q & 1) * 2 + (d >> 1)) << 4);
      unsigned lo = (unsigned)__shfl((int)pk0[d & 1], src);
      unsigned hi = (unsigned)__shfl((int)pk1[d & 1], src);
      ub.u4[d] = (q >= 2) ? hi : lo;
    }
    short8 bf2 = ub.s8;
    // GEMM2: out1[j][h] += a2t[j][i] * xw[i][h]
#pragma unroll
    for (int jt = 0; jt < NJT; ++jt) {
      short8 af = *(const short8*)&a2t[cur][jt * 16 + c][q * 8];
      acc2[jt] = __builtin_amdgcn_mfma_f32_16x16x32_bf16(af, bf2, acc2[jt], 0, 0, 0);
    }
    if (more) STAGE_WRITE_B(ic + 1, cur ^ 1);  // vb ready (long cover)
    __syncthreads();
  }

  // epilogue: h1 = relu(dinv_j*out1 + b1); g[h] = sum_j r_j*h1  (layer 2 collapsed)
  {
    const float bb = b1[w * 16 + c];
    float gp = 0.0f;
#pragma unroll
    for (int jt = 0; jt < NJT; ++jt) {
#pragma unroll
      for (int rg = 0; rg < 4; ++rg) {
        int j = jt * 16 + q * 4 + rg;
        if (j < NNODE) {
          float dj = dinv_l[j];
          float rj = dj * (rowsum[j] + dj);
          float o = fmaxf(dj * acc2[jt][rg] + bb, 0.0f);
          gp += rj * o;
        }
      }
    }
    gp += __shfl_xor(gp, 16);
    gp += __shfl_xor(gp, 32);
    if (q == 0) gs[w * 16 + c] = gp;
  }
  __syncthreads();
  // out = (g @ W2)/N + b2 : 4 partial segments then reduce
  {
    int h = tid & 127, seg = tid >> 7;
    float a = 0.0f;
#pragma unroll 8
    for (int cc = seg * 32; cc < seg * 32 + 32; ++cc) a += gs[cc] * W2[cc * HD + h];
    pt[seg][h] = a;
  }
  __syncthreads();
  if (tid < HD) {
    float a = pt[0][tid] + pt[1][tid] + pt[2][tid] + pt[3][tid];
    out[(size_t)s * HD + tid] = a * (1.0f / (float)NNODE) + b2[tid];
  }
}

extern "C" void kernel_launch(void* const* d_in, const int* in_sizes, int n_in,
                              void* d_out, int out_size, void* d_ws, size_t ws_size,
                              hipStream_t stream) {
  (void)in_sizes; (void)n_in; (void)out_size; (void)ws_size;
  const float* x = (const float*)d_in[0];
  // d_in[1] (adj) is dead: reference overwrites it with sparse(x, 0.2)
  const float* W1 = (const float*)d_in[2];
  const float* b1 = (const float*)d_in[3];
  const float* W2 = (const float*)d_in[4];
  const float* b2 = (const float*)d_in[5];
  float* out = (float*)d_out;

  unsigned short* wf = (unsigned short*)d_ws;         // 57344 B
  unsigned* vtit = (unsigned*)((char*)d_ws + 57344);  // 8192 B
  float* dinv_g = (float*)((char*)d_ws + 65536);      // 819200 B

  k_weights<<<dim3(14), dim3(256), 0, stream>>>(W1, wf);
  k_prep<<<dim3(NB), dim3(512), 0, stream>>>(x, vtit, dinv_g);
  k_main<<<dim3(NB), dim3(512), 0, stream>>>(x, wf, b1, W2, b2, vtit, dinv_g, out);
}

// Round 8
// 400.909 us; speedup vs baseline: 1.0222x; 1.0222x over previous
//
#include <hip/hip_runtime.h>

#define NB 1024
#define NNODE 200
#define NN2 40000
#define HD 128
#define KTOP 8000
#define NCH 7     // i-chunks of 32 (224 padded)
#define NJT 13    // j-tiles of 16 (208 padded)
#define XBS 232   // xb row stride (elems; 464 B; dword stride 116 == 20 mod 32 -> 2-way free)
#define A2S 40    // a2t row stride (80 B; dword stride 20 -> 2-way free)

#define WLO_BITS 0x3F47AE14u  // 0.78f
#define WHI_BITS 0x3F51EB85u  // 0.82f
#define CCAP 3072
#define C2CAP 64

typedef __attribute__((ext_vector_type(8))) short short8;
typedef __attribute__((ext_vector_type(4))) float f32x4;

__device__ __forceinline__ unsigned short f2bf(float f) {
  unsigned u = __float_as_uint(f);
  u = u + 0x7FFFu + ((u >> 16) & 1u);
  return (unsigned short)(u >> 16);
}

// JAX top_k selection predicate: value bits desc, flat index asc
__device__ __forceinline__ float maskv(float v, int idx, unsigned vt, int it) {
  unsigned b = __float_as_uint(v);
  return (b > vt || (b == vt && idx <= it)) ? v : 0.0f;
}

// ===== K0: pack W1 (200x128 f32) into bf16 B-fragment order ================
// frag t = (ks*8 + ht)*64 + lane; elem j: B[k=ks*32+(lane>>4)*8+j][h=ht*16+(lane&15)]
__global__ void k_weights(const float* __restrict__ W1, unsigned short* __restrict__ wf) {
  int t = blockIdx.x * 256 + threadIdx.x;
  if (t >= NCH * 8 * 64) return;
  int lane = t & 63;
  int ht = (t >> 6) & 7;
  int ks = t >> 9;
  int c = lane & 15, q = lane >> 4;
  int h = ht * 16 + c;
  unsigned short v[8];
#pragma unroll
  for (int j = 0; j < 8; ++j) {
    int k = ks * 32 + q * 8 + j;
    v[j] = f2bf((k < NNODE) ? W1[k * HD + h] : 0.0f);
  }
  uint4 u;
  u.x = (unsigned)v[0] | ((unsigned)v[1] << 16);
  u.y = (unsigned)v[2] | ((unsigned)v[3] << 16);
  u.z = (unsigned)v[4] | ((unsigned)v[5] << 16);
  u.w = (unsigned)v[6] | ((unsigned)v[7] << 16);
  ((uint4*)wf)[t] = u;
}

// ===== K1: per-sample exact top-8000 threshold + dinv, single x pass =======
// Standalone (34 KB LDS -> 4 blocks/CU). R5 lesson: fusing this with the GEMM
// kernel forced it to 2 blocks/CU (66 KB union) and cost ~60 us.
__global__ __launch_bounds__(512) void k_prep(const float* __restrict__ x,
                                              unsigned* __restrict__ vtit,
                                              float* __restrict__ dinv_g) {
  __shared__ union {
    struct { unsigned cb[CCAP]; int ci[CCAP]; } w;  // 24 KB (window + fallback cands)
    unsigned hist[4096];                            // 16 KB (fallback pass 1)
  } u;
  __shared__ unsigned sub[1024];
  __shared__ unsigned csum[512];
  __shared__ float degf[NNODE];
  __shared__ unsigned c2b[C2CAP];
  __shared__ int c2i[C2CAP];
  __shared__ int sc[4];
  __shared__ int cnt, cnt2, nhi_s, fbflag;
  __shared__ unsigned svt;
  __shared__ int sit;

  const int s = blockIdx.x, tid = threadIdx.x;
  const float* xp = x + (size_t)s * NN2;
  const float4* xp4 = (const float4*)xp;

  if (tid < NNODE) degf[tid] = 0.0f;
  if (tid == 0) { cnt = 0; cnt2 = 0; nhi_s = 0; fbflag = 0; }
  __syncthreads();

  // ---- single streaming pass: sure-colsums + window candidates + n_hi ----
  int nhi = 0;
#pragma unroll 4
  for (int e = tid; e < NN2 / 4; e += 512) {
    float4 f = xp4[e];
    int base = e * 4;
    float vv[4] = {f.x, f.y, f.z, f.w};
#pragma unroll
    for (int k = 0; k < 4; ++k) {
      unsigned bits = __float_as_uint(vv[k]);
      if (bits > WHI_BITS) {
        atomicAdd(&degf[(base + k) % NNODE], vv[k]);
        ++nhi;
      } else if (bits >= WLO_BITS) {
        int p = atomicAdd(&cnt, 1);
        if (p < CCAP) { u.w.cb[p] = bits; u.w.ci[p] = base + k; }
      }
    }
  }
#pragma unroll
  for (int m = 1; m < 64; m <<= 1) nhi += __shfl_xor(nhi, m);
  if ((tid & 63) == 0) atomicAdd(&nhi_s, nhi);
  __syncthreads();

  const int need = KTOP - nhi_s;
  const int c = cnt;
  bool window_ok = (need >= 1) && (c <= CCAP) && (need <= c);

  if (window_ok) {
    // ---- exact rank within candidates via sub-histogram on bits[21:12] ----
    for (int e = tid; e < 1024; e += 512) sub[e] = 0u;
    __syncthreads();
    for (int t = tid; t < c; t += 512) atomicAdd(&sub[(u.w.cb[t] >> 12) & 1023u], 1u);
    __syncthreads();
    if (tid < 128) {
      unsigned ss = 0;
#pragma unroll
      for (int k = 0; k < 8; ++k) ss += sub[tid * 8 + k];
      csum[tid] = ss;
    }
    __syncthreads();
    if (tid == 0) {
      int cum = 0, b2 = 0, need2 = need;
      for (int t = 127; t >= 0; --t) {
        int cs = (int)csum[t];
        if (cum + cs >= need) {
          for (int b = t * 8 + 7; b >= t * 8; --b) {
            int hb = (int)sub[b];
            if (cum + hb >= need) { b2 = b; need2 = need - cum; break; }
            cum += hb;
          }
          break;
        }
        cum += cs;
      }
      sc[0] = b2;
      sc[1] = need2;
    }
    __syncthreads();
    const unsigned b2 = (unsigned)sc[0];
    const int need2 = sc[1];
    for (int t = tid; t < c; t += 512) {
      if (((u.w.cb[t] >> 12) & 1023u) == b2) {
        int p = atomicAdd(&cnt2, 1);
        if (p < C2CAP) { c2b[p] = u.w.cb[t]; c2i[p] = u.w.ci[t]; }
      }
    }
    __syncthreads();
    if (cnt2 > C2CAP) {
      if (tid == 0) fbflag = 1;
    } else {
      const int c2 = cnt2;
      for (int t = tid; t < c2; t += 512) {
        unsigned vb = c2b[t];
        int vi = c2i[t];
        int rank = 0;
        for (int uu = 0; uu < c2; ++uu) {
          unsigned ub = c2b[uu];
          if (ub > vb || (ub == vb && c2i[uu] < vi)) ++rank;
        }
        if (rank == need2 - 1) { svt = vb; sit = vi; }
      }
    }
    __syncthreads();
    if (!fbflag) {
      const unsigned vt = svt;
      const int itx = sit;
      for (int t = tid; t < c; t += 512) {
        unsigned bits = u.w.cb[t];
        int e = u.w.ci[t];
        if (bits > vt || (bits == vt && e <= itx))
          atomicAdd(&degf[e % NNODE], __uint_as_float(bits));
      }
    }
  } else {
    if (tid == 0) fbflag = 1;
    __syncthreads();  // match barrier count shape (block-uniform anyway)
  }
  __syncthreads();

  if (fbflag) {
    // ================= fallback: verified two-pass radix select ============
    if (tid < NNODE) degf[tid] = 0.0f;
    for (int e = tid; e < 4096; e += 512) u.hist[e] = 0u;
    if (tid == 0) { cnt = 0; cnt2 = 0; }
    __syncthreads();
    for (int e = tid; e < NN2 / 4; e += 512) {
      float4 f = xp4[e];
      atomicAdd(&u.hist[__float_as_uint(f.x) >> 18], 1u);
      atomicAdd(&u.hist[__float_as_uint(f.y) >> 18], 1u);
      atomicAdd(&u.hist[__float_as_uint(f.z) >> 18], 1u);
      atomicAdd(&u.hist[__float_as_uint(f.w) >> 18], 1u);
    }
    __syncthreads();
    {
      unsigned ss = 0;
#pragma unroll
      for (int k = 0; k < 8; ++k) ss += u.hist[tid * 8 + k];
      csum[tid] = ss;
    }
    __syncthreads();
    if (tid == 0) {
      int cum = 0, bsel = 0, nd = KTOP;
      for (int t = 511; t >= 0; --t) {
        int cs = (int)csum[t];
        if (cum + cs >= KTOP) {
          for (int b = t * 8 + 7; b >= t * 8; --b) {
            int hb = (int)u.hist[b];
            if (cum + hb >= KTOP) { bsel = b; nd = KTOP - cum; break; }
            cum += hb;
          }
          break;
        }
        cum += cs;
      }
      sc[0] = bsel;
      sc[1] = nd;
    }
    __syncthreads();
    const int bsel = sc[0], nd = sc[1];
    // pass 2: candidates (bucket==bsel) + sure colsums (bucket>bsel)
    for (int e = tid; e < NN2 / 4; e += 512) {
      float4 f = xp4[e];
      int base = e * 4;
      float vv[4] = {f.x, f.y, f.z, f.w};
#pragma unroll
      for (int k = 0; k < 4; ++k) {
        unsigned bits = __float_as_uint(vv[k]);
        int bk = (int)(bits >> 18);
        if (bk > bsel) {
          atomicAdd(&degf[(base + k) % NNODE], vv[k]);
        } else if (bk == bsel) {
          int p = atomicAdd(&cnt, 1);
          if (p < CCAP) { u.w.cb[p] = bits; u.w.ci[p] = base + k; }
        }
      }
    }
    for (int e = tid; e < 1024; e += 512) sub[e] = 0u;
    __syncthreads();
    const int cc = cnt < CCAP ? cnt : CCAP;
    for (int t = tid; t < cc; t += 512) atomicAdd(&sub[(u.w.cb[t] >> 8) & 1023u], 1u);
    __syncthreads();
    if (tid < 128) {
      unsigned ss = 0;
#pragma unroll
      for (int k = 0; k < 8; ++k) ss += sub[tid * 8 + k];
      csum[tid] = ss;
    }
    __syncthreads();
    if (tid == 0) {
      int cum = 0, b2 = 0, need2 = nd;
      for (int t = 127; t >= 0; --t) {
        int cs = (int)csum[t];
        if (cum + cs >= nd) {
          for (int b = t * 8 + 7; b >= t * 8; --b) {
            int hb = (int)sub[b];
            if (cum + hb >= nd) { b2 = b; need2 = nd - cum; break; }
            cum += hb;
          }
          break;
        }
        cum += cs;
      }
      sc[2] = b2;
      sc[3] = need2;
    }
    __syncthreads();
    const unsigned key = ((unsigned)bsel << 10) | (unsigned)sc[2];
    const int need2 = sc[3];
    for (int t = tid; t < cc; t += 512) {
      if ((u.w.cb[t] >> 8) == key) {
        int p = atomicAdd(&cnt2, 1);
        if (p < C2CAP) { c2b[p] = u.w.cb[t]; c2i[p] = u.w.ci[t]; }
      }
    }
    __syncthreads();
    {
      int c2 = cnt2 < C2CAP ? cnt2 : C2CAP;
      for (int t = tid; t < c2; t += 512) {
        unsigned vb = c2b[t];
        int vi = c2i[t];
        int rank = 0;
        for (int uu = 0; uu < c2; ++uu) {
          unsigned ub = c2b[uu];
          if (ub > vb || (ub == vb && c2i[uu] < vi)) ++rank;
        }
        if (rank == need2 - 1) { svt = vb; sit = vi; }
      }
    }
    __syncthreads();
    const unsigned vt = svt;
    const int itx = sit;
    for (int t = tid; t < cc; t += 512) {
      unsigned bits = u.w.cb[t];
      int e = u.w.ci[t];
      if (bits > vt || (bits == vt && e <= itx))
        atomicAdd(&degf[e % NNODE], __uint_as_float(bits));
    }
    __syncthreads();
  }

  if (tid < NNODE) dinv_g[s * NNODE + tid] = 1.0f / sqrtf(1.0f + degf[tid]);
  if (tid == 0) {
    vtit[s * 2 + 0] = svt;
    vtit[s * 2 + 1] = (unsigned)sit;
  }
}

// ---- staging macros (hand-inlined) -----------------------------------------
// T14 split: LOADs issue global reads into va/vb regs at chunk TOP; both
// WRITEs run at chunk END (R7 lesson: write_A right after GEMM1 had only
// ~200cyc cover vs ~600cyc L3 latency -> ~400cyc stall/chunk; at chunk end
// the cover is the full chunk body).
#define STAGE_LOAD_A(ic_)                                              \
  {                                                                    \
    const int gi = (ic_)*32 + r_;                                      \
    const bool rowok = gi < NNODE;                                     \
    const int rb = gi * NNODE;                                         \
    _Pragma("unroll") for (int itc = 0; itc < 7; ++itc) {              \
      int col = c0_ + itc * 16; /* <=111, always valid */              \
      va[itc] = rowok ? xp[rb + col] : 0.0f;                           \
    }                                                                  \
  }

#define STAGE_LOAD_B(ic_)                                              \
  {                                                                    \
    const int gi = (ic_)*32 + r_;                                      \
    const bool rowok = gi < NNODE;                                     \
    const int rb = gi * NNODE;                                         \
    _Pragma("unroll") for (int itc = 7; itc < 13; ++itc) {             \
      int col = c0_ + itc * 16;                                        \
      vb[itc - 7] = (rowok && col < NNODE) ? xp[rb + col] : 0.0f;      \
    }                                                                  \
  }

#define STAGE_WRITE_A(ic_, bb_)                                        \
  {                                                                    \
    const int gi = (ic_)*32 + r_;                                      \
    const float di = dinv_l[gi];                                       \
    const int rb = gi * NNODE;                                         \
    rsA = 0.0f;                                                        \
    _Pragma("unroll") for (int itc = 0; itc < 7; ++itc) {              \
      int col = c0_ + itc * 16;                                        \
      float val = va[itc];                                             \
      unsigned short xbv = f2bf(val);                                  \
      float am = maskv(val, rb + col, vt, itx);                        \
      rsA += am * dinv_l[col];                                         \
      if (gi == col) am += 1.0f;                                       \
      xb[bb_][r_][col] = xbv;                                          \
      a2t[bb_][col][r_] = f2bf(am * di);                               \
    }                                                                  \
  }

#define STAGE_WRITE_B(ic_, bb_)                                        \
  {                                                                    \
    const int gi = (ic_)*32 + r_;                                      \
    const float di = dinv_l[gi];                                       \
    const int rb = gi * NNODE;                                         \
    float rs = rsA;                                                    \
    _Pragma("unroll") for (int itc = 7; itc < 13; ++itc) {             \
      int col = c0_ + itc * 16;                                        \
      unsigned short xbv = 0, a2v = 0;                                 \
      if (col < NNODE) {                                               \
        float val = vb[itc - 7];                                       \
        xbv = f2bf(val);                                               \
        float am = maskv(val, rb + col, vt, itx);                      \
        rs += am * dinv_l[col];                                        \
        if (gi == col) am += 1.0f;                                     \
        a2v = f2bf(am * di);                                           \
      }                                                                \
      xb[bb_][r_][col] = xbv;                                          \
      a2t[bb_][col][r_] = a2v;                                         \
    }                                                                  \
    xb[bb_][r_][208 + c0_] = 0; /* k-pad 208..223 */                   \
    rs += __shfl_xor(rs, 1);                                           \
    rs += __shfl_xor(rs, 2);                                           \
    rs += __shfl_xor(rs, 4);                                           \
    rs += __shfl_xor(rs, 8);                                           \
    if (c0_ == 0) atomicAdd(&rowsum[gi], rs);                          \
  }

// ===== K2: fused chain GEMM, wave-self-contained, shfl transpose ===========
// R6 lesson: bfr[7] persistent (28 VGPR) overflowed the 128-reg budget.
// Per-chunk wfr[] reloads (L1-hot) halved spill; R7 counters show residual
// spill is overlapped (not the limiter) -- the exposed va-load stall was.
__global__ __launch_bounds__(512, 4) void k_main(
    const float* __restrict__ x, const unsigned short* __restrict__ wf,
    const float* __restrict__ b1, const float* __restrict__ W2,
    const float* __restrict__ b2, const unsigned* __restrict__ vtit,
    const float* __restrict__ dinv_g, float* __restrict__ out) {
  __shared__ unsigned short xb[2][32][XBS];    // x chunk bf16 [i][k]
  __shared__ unsigned short a2t[2][208][A2S];  // Ah_ij*dinv_i bf16 [j][i]
  __shared__ float rowsum[224];
  __shared__ float dinv_l[224];
  __shared__ float gs[HD];
  __shared__ float pt[4][HD];

  const int s = blockIdx.x;
  const int tid = threadIdx.x;
  const int lane = tid & 63;
  const int w = tid >> 6;  // wave 0..7 owns h-tile w
  const int c = lane & 15;
  const int q = lane >> 4;
  const float* xp = x + (size_t)s * NN2;
  const short8* wfp = (const short8*)wf;

  if (tid < 224) {
    dinv_l[tid] = (tid < NNODE) ? dinv_g[s * NNODE + tid] : 0.0f;
    rowsum[tid] = 0.0f;
  }
  const unsigned vt = vtit[s * 2];
  const int itx = (int)vtit[s * 2 + 1];
  const int r_ = tid >> 4, c0_ = tid & 15;

  float va[7], vb[6], rsA;

  // issue chunk-0 x loads immediately
  STAGE_LOAD_A(0);
  STAGE_LOAD_B(0);

  f32x4 acc2[NJT];
#pragma unroll
  for (int jt = 0; jt < NJT; ++jt) acc2[jt] = (f32x4){0.f, 0.f, 0.f, 0.f};

  __syncthreads();  // dinv_l ready
  STAGE_WRITE_A(0, 0);
  STAGE_WRITE_B(0, 0);
  __syncthreads();

  for (int ic = 0; ic < NCH; ++ic) {
    const int cur = ic & 1;
    const bool more = (ic + 1 < NCH);
    // W1 fragments for this chunk's GEMM1, issued FIRST (oldest in vm queue ->
    // MFMA's waitcnt doesn't drain the x loads behind them). L1-hit after ic=0.
    short8 wfr[NCH];
#pragma unroll
    for (int ks = 0; ks < NCH; ++ks) wfr[ks] = wfp[(ks * 8 + w) * 64 + lane];
    if (more) {
      STAGE_LOAD_A(ic + 1);  // issue at top; consumed at chunk END (full cover)
      STAGE_LOAD_B(ic + 1);
    }
    // GEMM1: D(it)[i16][hc] for i-tiles 0,1 of this chunk, h-tile w
    f32x4 a0 = (f32x4){0.f, 0.f, 0.f, 0.f}, a1 = (f32x4){0.f, 0.f, 0.f, 0.f};
#pragma unroll
    for (int ks = 0; ks < NCH; ++ks) {
      short8 af0 = *(const short8*)&xb[cur][c][ks * 32 + q * 8];
      short8 af1 = *(const short8*)&xb[cur][16 + c][ks * 32 + q * 8];
      a0 = __builtin_amdgcn_mfma_f32_16x16x32_bf16(af0, wfr[ks], a0, 0, 0, 0);
      a1 = __builtin_amdgcn_mfma_f32_16x16x32_bf16(af1, wfr[ks], a1, 0, 0, 0);
    }
    // pack C-layout rows (q*4+rg) to bf16 dword pairs
    unsigned pk0[2], pk1[2];
    pk0[0] = (unsigned)f2bf(a0[0]) | ((unsigned)f2bf(a0[1]) << 16);
    pk0[1] = (unsigned)f2bf(a0[2]) | ((unsigned)f2bf(a0[3]) << 16);
    pk1[0] = (unsigned)f2bf(a1[0]) | ((unsigned)f2bf(a1[1]) << 16);
    pk1[1] = (unsigned)f2bf(a1[2]) | ((unsigned)f2bf(a1[3]) << 16);
    // in-register transpose: C-layout -> GEMM2 B-fragment (k=i-local, n=h)
    union {
      unsigned u4[4];
      short8 s8;
    } ub;
#pragma unroll
    for (int d = 0; d < 4; ++d) {
      int src = c + (((q & 1) * 2 + (d >> 1)) << 4);
      unsigned lo = (unsigned)__shfl((int)pk0[d & 1], src);
      unsigned hi = (unsigned)__shfl((int)pk1[d & 1], src);
      ub.u4[d] = (q >= 2) ? hi : lo;
    }
    short8 bf2 = ub.s8;
    // GEMM2: out1[j][h] += a2t[j][i] * xw[i][h]
#pragma unroll
    for (int jt = 0; jt < NJT; ++jt) {
      short8 af = *(const short8*)&a2t[cur][jt * 16 + c][q * 8];
      acc2[jt] = __builtin_amdgcn_mfma_f32_16x16x32_bf16(af, bf2, acc2[jt], 0, 0, 0);
    }
    if (more) {
      STAGE_WRITE_A(ic + 1, cur ^ 1);  // va: full-chunk cover, ~no stall
      STAGE_WRITE_B(ic + 1, cur ^ 1);  // vb: full-chunk cover
    }
    __syncthreads();
  }

  // epilogue: h1 = relu(dinv_j*out1 + b1); g[h] = sum_j r_j*h1  (layer 2 collapsed)
  {
    const float bb = b1[w * 16 + c];
    float gp = 0.0f;
#pragma unroll
    for (int jt = 0; jt < NJT; ++jt) {
#pragma unroll
      for (int rg = 0; rg < 4; ++rg) {
        int j = jt * 16 + q * 4 + rg;
        if (j < NNODE) {
          float dj = dinv_l[j];
          float rj = dj * (rowsum[j] + dj);
          float o = fmaxf(dj * acc2[jt][rg] + bb, 0.0f);
          gp += rj * o;
        }
      }
    }
    gp += __shfl_xor(gp, 16);
    gp += __shfl_xor(gp, 32);
    if (q == 0) gs[w * 16 + c] = gp;
  }
  __syncthreads();
  // out = (g @ W2)/N + b2 : 4 partial segments then reduce
  {
    int h = tid & 127, seg = tid >> 7;
    float a = 0.0f;
#pragma unroll 8
    for (int cc = seg * 32; cc < seg * 32 + 32; ++cc) a += gs[cc] * W2[cc * HD + h];
    pt[seg][h] = a;
  }
  __syncthreads();
  if (tid < HD) {
    float a = pt[0][tid] + pt[1][tid] + pt[2][tid] + pt[3][tid];
    out[(size_t)s * HD + tid] = a * (1.0f / (float)NNODE) + b2[tid];
  }
}

extern "C" void kernel_launch(void* const* d_in, const int* in_sizes, int n_in,
                              void* d_out, int out_size, void* d_ws, size_t ws_size,
                              hipStream_t stream) {
  (void)in_sizes; (void)n_in; (void)out_size; (void)ws_size;
  const float* x = (const float*)d_in[0];
  // d_in[1] (adj) is dead: reference overwrites it with sparse(x, 0.2)
  const float* W1 = (const float*)d_in[2];
  const float* b1 = (const float*)d_in[3];
  const float* W2 = (const float*)d_in[4];
  const float* b2 = (const float*)d_in[5];
  float* out = (float*)d_out;

  unsigned short* wf = (unsigned short*)d_ws;         // 57344 B
  unsigned* vtit = (unsigned*)((char*)d_ws + 57344);  // 8192 B
  float* dinv_g = (float*)((char*)d_ws + 65536);      // 819200 B

  k_weights<<<dim3(14), dim3(256), 0, stream>>>(W1, wf);
  k_prep<<<dim3(NB), dim3(512), 0, stream>>>(x, vtit, dinv_g);
  k_main<<<dim3(NB), dim3(512), 0, stream>>>(x, wf, b1, W2, b2, vtit, dinv_g, out);
}